// Round 4
// baseline (838.768 us; speedup 1.0000x reference)
//
#include <hip/hip_runtime.h>

// Fused attention fwd: R = softmax(Q K^T / sqrt(D)) V, plus attn weights P.
// B=16, LQ=LK=2048, D=128, fp32 in/out.
//
// Round 7. r6 post-mortem: bank conflicts halved -> dur unchanged => LDS was
// never critical. The invariant across r3/r5/r6: effective P-write BW pins
// at ~1.4 TB/s (dur = WRITE_SIZE/1.4TB/s predicts all three within 3%) with
// every compute counter idle => WRITE-STREAM BOUND. Cause: each iter writes
// a 64-row x 256B column slice of P (256B bursts at 8KB stride, x512 blocks
// concurrently) -> DRAM page thrash; plus store-acks couple into next-iter
// prefetch via the in-order vmcnt queue.
// FIX: buffer FOUR key-tiles of P in LDS (Ps4[64][264] bf16, 33.8KB) and
// flush every 4th iter as 1KB-contiguous bursts per row (quad = 256B
// contiguous, 4 quads/row). 4x page locality, 4x fewer store-drain points.
// LDS 70.7KB/block -> still 2 blocks/CU (= the 512-block grid's own cap).
// Kept: swapped QK^T (per-lane scalar softmax), lgkm-only barriers, b128
// V staging, coalesced K staging, quad P pattern, nontemporal stores.

#define NB  16
#define SLQ 2048
#define SLK 2048
#define DH  128
#define BQ  64
#define BK  64

typedef __bf16 bf16;
typedef bf16  bf16x8 __attribute__((ext_vector_type(8)));
typedef bf16  bf16x4 __attribute__((ext_vector_type(4)));
typedef float f32x2  __attribute__((ext_vector_type(2)));
typedef float f32x4  __attribute__((ext_vector_type(4)));
typedef float f32x16 __attribute__((ext_vector_type(16)));

#define SCALE 0.088388347648318447f  // 1/sqrt(128)

__device__ __forceinline__ f32x16 mfma32(bf16x8 a, bf16x8 b, f32x16 c) {
    return __builtin_amdgcn_mfma_f32_32x32x16_bf16(a, b, c, 0, 0, 0);
}

__device__ __forceinline__ bf16x8 cvt8(f32x4 v0, f32x4 v1) {
    bf16x8 r;
    r[0] = (bf16)v0[0]; r[1] = (bf16)v0[1]; r[2] = (bf16)v0[2]; r[3] = (bf16)v0[3];
    r[4] = (bf16)v1[0]; r[5] = (bf16)v1[1]; r[6] = (bf16)v1[2]; r[7] = (bf16)v1[3];
    return r;
}

__device__ __forceinline__ bf16x8 cvt8s(f32x4 v0, f32x4 v1, float s) {
    bf16x8 r;
    r[0] = (bf16)(v0[0] * s); r[1] = (bf16)(v0[1] * s);
    r[2] = (bf16)(v0[2] * s); r[3] = (bf16)(v0[3] * s);
    r[4] = (bf16)(v1[0] * s); r[5] = (bf16)(v1[1] * s);
    r[6] = (bf16)(v1[2] * s); r[7] = (bf16)(v1[3] * s);
    return r;
}

// Workgroup barrier waiting only on LDS ops (lgkmcnt), NOT vmcnt -- P stores
// and prefetch loads stream across it.
__device__ __forceinline__ void barrier_lgkm() {
    asm volatile("s_waitcnt lgkmcnt(0)" ::: "memory");
    __builtin_amdgcn_s_barrier();
    asm volatile("" ::: "memory");
}

__global__ __launch_bounds__(256, 2)
void attn_fused(const float* __restrict__ Q, const float* __restrict__ K,
                const float* __restrict__ V, float* __restrict__ Rout,
                float* __restrict__ Pout) {
    const int b = blockIdx.x, qt = blockIdx.y;   // batch-major: XCD = b % 8
    const int tid  = threadIdx.x;
    const int wave = tid >> 6, lane = tid & 63;
    const int n31 = lane & 31, h = lane >> 5;
    const int wm = wave & 1, wn = wave >> 1;     // pass-2 tiling only

    // LDS: Ks[64][136] @0 (17408) | Vt[128][72] @17408 (18432) |
    // Ps4[64][264] @35840 (33792, 4 key-tiles) | rsum @69632.
    // Pass-1 aliases Ks1[128][136] (34816) over Ks+Vt.
    __shared__ __align__(16) char smem[69632 + 1024];
    bf16 (*Ks)[136]  = (bf16(*)[136])smem;
    bf16 (*Ks1)[136] = (bf16(*)[136])smem;
    bf16 (*Vt)[72]   = (bf16(*)[72])(smem + 17408);
    bf16 (*Ps4)[264] = (bf16(*)[264])(smem + 35840);
    float* rsum      = (float*)(smem + 69632);   // [wave][64]

    const float* Qb = Q + ((size_t)b * SLQ + qt * BQ) * DH;
    const float* Kb = K + (size_t)b * SLK * DH;
    const float* Vb = V + (size_t)b * SLK * DH;
    float* Rb = Rout + ((size_t)b * SLQ + qt * BQ) * DH;
    float* Pb = Pout + ((size_t)b * SLQ + qt * BQ) * SLK;

    // Q B-frags for BOTH q-halves (pass 1 uses both; pass 2 selects wm half).
    bf16x8 aq0[8], aq1[8];
    {
        const float* qp0 = Qb + (size_t)n31 * DH + h * 8;
        const float* qp1 = qp0 + 32 * DH;
#pragma unroll
        for (int kk = 0; kk < 8; ++kk) {
            aq0[kk] = cvt8s(*(const f32x4*)(qp0 + kk * 16),
                            *(const f32x4*)(qp0 + kk * 16 + 4), SCALE);
            aq1[kk] = cvt8s(*(const f32x4*)(qp1 + kk * 16),
                            *(const f32x4*)(qp1 + kk * 16 + 4), SCALE);
        }
    }

    // ---------------- pass 1: row sums (BK=128, 16 tiles) ----------------
    // Wave w owns keys w*32.. of each tile, ALL 64 q (no duplicated kf reads).
    float ps0 = 0.f, ps1 = 0.f;
    {
        f32x4 kreg[16];
#pragma unroll
        for (int i = 0; i < 8; ++i) {
            int f = tid + i * 256, row = f >> 4, g = f & 15;
            const float* kp = Kb + (size_t)row * DH + g * 8;
            kreg[2 * i]     = *(const f32x4*)kp;
            kreg[2 * i + 1] = *(const f32x4*)(kp + 4);
        }
        for (int kt = 0; kt < 16; ++kt) {
            barrier_lgkm();   // prior-iter frag reads done
#pragma unroll
            for (int i = 0; i < 8; ++i) {
                int f = tid + i * 256, row = f >> 4, g = f & 15;
                *(bf16x8*)&Ks1[row][g * 8] = cvt8(kreg[2 * i], kreg[2 * i + 1]);
            }
            barrier_lgkm();   // staging visible
            if (kt + 1 < 16) {
#pragma unroll
                for (int i = 0; i < 8; ++i) {
                    int f = tid + i * 256, row = f >> 4, g = f & 15;
                    const float* kp = Kb + (size_t)((kt + 1) * 128 + row) * DH + g * 8;
                    kreg[2 * i]     = *(const f32x4*)kp;
                    kreg[2 * i + 1] = *(const f32x4*)(kp + 4);
                }
            }
            f32x16 c0 = (f32x16)0.0f, c1 = (f32x16)0.0f;
#pragma unroll
            for (int kk = 0; kk < 8; ++kk) {
                bf16x8 kf = *(const bf16x8*)&Ks1[wave * 32 + n31][kk * 16 + h * 8];
                c0 = mfma32(kf, aq0[kk], c0);
                c1 = mfma32(kf, aq1[kk], c1);
            }
#pragma unroll
            for (int r = 0; r < 16; ++r) { ps0 += __expf(c0[r]); ps1 += __expf(c1[r]); }
        }
    }

    // prefetch pass-2 tile 0 (K/V re-reads are L2-hot); overlaps reduction
    const int dv = 2 * lane;          // V-stage: this lane owns d = dv, dv+1
    f32x4 kreg2[8];
    f32x2 vr0[8], vr1[8];             // [j] = V[k0+j][dv..dv+1]
#pragma unroll
    for (int i = 0; i < 4; ++i) {
        int f = tid + i * 256, row = f >> 4, g = f & 15;
        const float* kp = Kb + (size_t)row * DH + g * 8;
        kreg2[2 * i]     = *(const f32x4*)kp;
        kreg2[2 * i + 1] = *(const f32x4*)(kp + 4);
    }
#pragma unroll
    for (int j = 0; j < 8; ++j) {
        vr0[j] = *(const f32x2*)(Vb + (size_t)(8 * wave + j) * DH + dv);
        vr1[j] = *(const f32x2*)(Vb + (size_t)(8 * wave + 32 + j) * DH + dv);
    }

    // merge h halves (shfl), then the 4 wave key-groups via LDS
    ps0 += __shfl_xor(ps0, 32);
    ps1 += __shfl_xor(ps1, 32);
    if (lane < 32) {
        rsum[wave * 64 + n31]      = ps0;
        rsum[wave * 64 + 32 + n31] = ps1;
    }
    barrier_lgkm();
    const int qrow = wm * 32 + n31;
    const float rinv = 1.0f / (rsum[qrow] + rsum[64 + qrow] +
                               rsum[128 + qrow] + rsum[192 + qrow]);

    // pass-2 Q frags: select this wave's q-half
    bf16x8 aqp[8];
#pragma unroll
    for (int kk = 0; kk < 8; ++kk) aqp[kk] = wm ? aq1[kk] : aq0[kk];

    f32x16 racc[2];
    racc[0] = (f32x16)0.0f;
    racc[1] = (f32x16)0.0f;

    // ---------------- pass 2: P store + PV (BK=64, 32 tiles) ----------------
    for (int kt = 0; kt < 32; ++kt) {
        barrier_lgkm();   // A: prev-iter PV/flush LDS reads done
        // stage K tile [k][d] (coalesced regs -> LDS)
#pragma unroll
        for (int i = 0; i < 4; ++i) {
            int f = tid + i * 256, row = f >> 4, g = f & 15;
            *(bf16x8*)&Ks[row][g * 8] = cvt8(kreg2[2 * i], kreg2[2 * i + 1]);
        }
        // stage V^T [d][k]: k-contiguous b128 writes into XOR-swizzled blocks
        {
            int sw = (dv >> 3) & 7;
            bf16x8 w0, w1;
#pragma unroll
            for (int j = 0; j < 8; ++j) { w0[j] = (bf16)vr0[j][0]; w1[j] = (bf16)vr0[j][1]; }
            int pb = wave ^ sw;
            *(bf16x8*)&Vt[dv][pb * 8]     = w0;
            *(bf16x8*)&Vt[dv + 1][pb * 8] = w1;
#pragma unroll
            for (int j = 0; j < 8; ++j) { w0[j] = (bf16)vr1[j][0]; w1[j] = (bf16)vr1[j][1]; }
            pb = (wave + 4) ^ sw;
            *(bf16x8*)&Vt[dv][pb * 8]     = w0;
            *(bf16x8*)&Vt[dv + 1][pb * 8] = w1;
        }
        barrier_lgkm();   // B: Ks/Vt visible

        // QK^T swapped: c = S^T sub-tile (keys wn*32.., q-col = lane)
        f32x16 c = (f32x16)0.0f;
#pragma unroll
        for (int kk = 0; kk < 8; ++kk) {
            bf16x8 kf = *(const bf16x8*)&Ks[wn * 32 + n31][kk * 16 + h * 8];
            c = mfma32(kf, aqp[kk], c);
        }
        // softmax -> Ps4 slice (kt&3), 4x b64 writes
        const int sl = (kt & 3) * 64;
#pragma unroll
        for (int g = 0; g < 4; ++g) {
            bf16x4 pw;
            pw[0] = (bf16)(__expf(c[4 * g + 0]) * rinv);
            pw[1] = (bf16)(__expf(c[4 * g + 1]) * rinv);
            pw[2] = (bf16)(__expf(c[4 * g + 2]) * rinv);
            pw[3] = (bf16)(__expf(c[4 * g + 3]) * rinv);
            *(bf16x4*)&Ps4[qrow][sl + wn * 32 + 4 * h + 8 * g] = pw;
        }

        // prefetch next tile (issued BEFORE any stores this iter, so later
        // counted vmcnt waits on loads don't force store drains)
        if (kt + 1 < 32) {
#pragma unroll
            for (int i = 0; i < 4; ++i) {
                int f = tid + i * 256, row = f >> 4, g = f & 15;
                const float* kp = Kb + (size_t)((kt + 1) * 64 + row) * DH + g * 8;
                kreg2[2 * i]     = *(const f32x4*)kp;
                kreg2[2 * i + 1] = *(const f32x4*)(kp + 4);
            }
            const float* vb = Vb + (size_t)(kt + 1) * 64 * DH + dv;
#pragma unroll
            for (int j = 0; j < 8; ++j) {
                vr0[j] = *(const f32x2*)(vb + (size_t)(8 * wave + j) * DH);
                vr1[j] = *(const f32x2*)(vb + (size_t)(8 * wave + 32 + j) * DH);
            }
        }
        barrier_lgkm();   // C: Ps4 slice visible (cross-wave for PV A-frags)

        // P flush every 4 tiles: 256 keys -> 1KB contiguous burst per row
        // (quad covers 256B contiguous; 4 quads tile the 1KB row slice)
        if ((kt & 3) == 3) {
            int prow = tid >> 2, pc4 = (tid & 3) * 16;
            float* dst = Pb + (size_t)prow * SLK + (kt - 3) * 64;
#pragma unroll
            for (int u = 0; u < 4; ++u) {
                bf16x8 p0 = *(const bf16x8*)&Ps4[prow][u * 64 + pc4];
                bf16x8 p1 = *(const bf16x8*)&Ps4[prow][u * 64 + pc4 + 8];
                float* d = dst + u * 64 + pc4;
                f32x4 o;
                o[0] = (float)p0[0]; o[1] = (float)p0[1];
                o[2] = (float)p0[2]; o[3] = (float)p0[3];
                __builtin_nontemporal_store(o, (f32x4*)d);
                o[0] = (float)p0[4]; o[1] = (float)p0[5];
                o[2] = (float)p0[6]; o[3] = (float)p0[7];
                __builtin_nontemporal_store(o, (f32x4*)(d + 4));
                o[0] = (float)p1[0]; o[1] = (float)p1[1];
                o[2] = (float)p1[2]; o[3] = (float)p1[3];
                __builtin_nontemporal_store(o, (f32x4*)(d + 8));
                o[0] = (float)p1[4]; o[1] = (float)p1[5];
                o[2] = (float)p1[6]; o[3] = (float)p1[7];
                __builtin_nontemporal_store(o, (f32x4*)(d + 12));
            }
        }

        // PV: R rows wm*32+.., d-cols wn*64 + t*32 + n31
#pragma unroll
        for (int kk = 0; kk < 4; ++kk) {
            bf16x8 ap = *(const bf16x8*)&Ps4[qrow][sl + kk * 16 + 8 * h];
#pragma unroll
            for (int t = 0; t < 2; ++t) {
                int d = wn * 64 + t * 32 + n31;
                int pb = (2 * kk + h) ^ ((d >> 3) & 7);
                bf16x8 bv = *(const bf16x8*)&Vt[d][pb * 8];
                racc[t] = mfma32(ap, bv, racc[t]);
            }
        }
    }

    // epilogue: R store (C layout: col = wn*64+t*32+n31, row per reg map)
#pragma unroll
    for (int t = 0; t < 2; ++t)
#pragma unroll
        for (int r = 0; r < 16; ++r) {
            int row = wm * 32 + (r & 3) + 8 * (r >> 2) + 4 * h;
            int d   = wn * 64 + t * 32 + n31;
            __builtin_nontemporal_store(racc[t][r], &Rb[(size_t)row * DH + d]);
        }
}

extern "C" void kernel_launch(void* const* d_in, const int* in_sizes, int n_in,
                              void* d_out, int out_size, void* d_ws, size_t ws_size,
                              hipStream_t stream) {
    (void)in_sizes; (void)n_in; (void)out_size; (void)d_ws; (void)ws_size;
    const float* Q = (const float*)d_in[0];
    const float* K = (const float*)d_in[1];
    const float* V = (const float*)d_in[2];
    float* R = (float*)d_out;
    float* P = (float*)d_out + (size_t)NB * SLQ * DH;

    dim3 grid(NB, SLQ / BQ);  // 512 blocks, batch-major for XCD L2 locality
    attn_fused<<<grid, 256, 0, stream>>>(Q, K, V, R, P);
}

// Round 5
// 525.049 us; speedup vs baseline: 1.5975x; 1.5975x over previous
//
#include <hip/hip_runtime.h>

// Fused attention fwd: R = softmax(Q K^T / sqrt(D)) V, plus attn weights P.
// B=16, LQ=LK=2048, D=128, fp32 in/out.
//
// Round 8. r7 post-mortem: flush broke full-line-per-instruction coverage
// (quad lanes 64B apart, 16B each) -> NT write amplification 2.56x. Deeper:
// r6's null (LDS -30%, conflicts -50%, dur unchanged) kills the LDS theory,
// and the "constant 1.4TB/s write BW" across r3/r5/r6 is epiphenomenal --
// dur = 48 barrier-locked iters x ~4.1us at 2 blocks/CU with every pipe
// <=60%: LATENCY-BOUND, UNDER-OCCUPIED (2 waves/SIMD).
// FIX: BQ=32 -> grid 1024 blocks, LDS 40,448B <= 40KB -> 4 blocks/CU =
// 4 waves/SIMD (2x latency hiding). launch_bounds(256,4). Per-block work
// halves; iteration count per block unchanged but 2x blocks overlap per CU.
//  - pass 1: wave w owns keys w*32 (all 32 q), scalar psum (swapped QK^T)
//  - pass 2: QK+softmax+Ps on waves 0,1 (wn=wave&1 key-half); PV on all 4
//    waves (32 d-cols each); no duplicated FLOPs
//  - P store: 32 rows x 8 thr, lanes 0-7 cover 128B contiguous per instr
//    (full-line NT stores, the r5-proven property)
//  - rsum aliases Ps (rinv loaded into reg before first Ps write)
// Kept: swapped QK^T, lgkm-only barriers, b128 V staging, coalesced K
// staging, per-iter P store, NT stores, batch-major grid.

#define NB  16
#define SLQ 2048
#define SLK 2048
#define DH  128
#define BQ  32
#define BK  64

typedef __bf16 bf16;
typedef bf16  bf16x8 __attribute__((ext_vector_type(8)));
typedef bf16  bf16x4 __attribute__((ext_vector_type(4)));
typedef float f32x2  __attribute__((ext_vector_type(2)));
typedef float f32x4  __attribute__((ext_vector_type(4)));
typedef float f32x16 __attribute__((ext_vector_type(16)));

#define SCALE 0.088388347648318447f  // 1/sqrt(128)

__device__ __forceinline__ f32x16 mfma32(bf16x8 a, bf16x8 b, f32x16 c) {
    return __builtin_amdgcn_mfma_f32_32x32x16_bf16(a, b, c, 0, 0, 0);
}

__device__ __forceinline__ bf16x8 cvt8(f32x4 v0, f32x4 v1) {
    bf16x8 r;
    r[0] = (bf16)v0[0]; r[1] = (bf16)v0[1]; r[2] = (bf16)v0[2]; r[3] = (bf16)v0[3];
    r[4] = (bf16)v1[0]; r[5] = (bf16)v1[1]; r[6] = (bf16)v1[2]; r[7] = (bf16)v1[3];
    return r;
}

__device__ __forceinline__ bf16x8 cvt8s(f32x4 v0, f32x4 v1, float s) {
    bf16x8 r;
    r[0] = (bf16)(v0[0] * s); r[1] = (bf16)(v0[1] * s);
    r[2] = (bf16)(v0[2] * s); r[3] = (bf16)(v0[3] * s);
    r[4] = (bf16)(v1[0] * s); r[5] = (bf16)(v1[1] * s);
    r[6] = (bf16)(v1[2] * s); r[7] = (bf16)(v1[7 - 7 + 3] * s);  // v1[3]
    r[7] = (bf16)(v1[3] * s);
    return r;
}

// Workgroup barrier waiting only on LDS ops (lgkmcnt), NOT vmcnt -- P stores
// and prefetch loads stream across it.
__device__ __forceinline__ void barrier_lgkm() {
    asm volatile("s_waitcnt lgkmcnt(0)" ::: "memory");
    __builtin_amdgcn_s_barrier();
    asm volatile("" ::: "memory");
}

__global__ __launch_bounds__(256, 4)
void attn_fused(const float* __restrict__ Q, const float* __restrict__ K,
                const float* __restrict__ V, float* __restrict__ Rout,
                float* __restrict__ Pout) {
    const int b = blockIdx.x, qt = blockIdx.y;   // batch-major: XCD = b % 8
    const int tid  = threadIdx.x;
    const int wave = tid >> 6, lane = tid & 63;
    const int n31 = lane & 31, h = lane >> 5;
    const int wn = wave & 1;                     // pass-2 QK key-half (waves 0,1)

    // LDS: Ks[64][136] @0 (17408) | Vt[128][72] @17408 (18432) |
    // Ps[32][72] @35840 (4608). Total 40448 <= 40960 (4 blocks/CU).
    // Pass-1 aliases Ks1[128][136] (34816) over Ks+Vt; rsum aliases Ps.
    __shared__ __align__(16) char smem[40448];
    bf16 (*Ks)[136]  = (bf16(*)[136])smem;
    bf16 (*Ks1)[136] = (bf16(*)[136])smem;
    bf16 (*Vt)[72]   = (bf16(*)[72])(smem + 17408);
    bf16 (*Ps)[72]   = (bf16(*)[72])(smem + 35840);
    float* rsum      = (float*)(smem + 35840);   // [4][32], alias over Ps

    const float* Qb = Q + ((size_t)b * SLQ + qt * BQ) * DH;
    const float* Kb = K + (size_t)b * SLK * DH;
    const float* Vb = V + (size_t)b * SLK * DH;
    float* Rb = Rout + ((size_t)b * SLQ + qt * BQ) * DH;
    float* Pb = Pout + ((size_t)b * SLQ + qt * BQ) * SLK;

    // Q B-frags (32 q rows; every wave loads the same rows -- L1-hot).
    // aq[kk] per lane = Q[n31][kk*16+8h .. +7] * SCALE.
    bf16x8 aq[8];
    {
        const float* qp = Qb + (size_t)n31 * DH + h * 8;
#pragma unroll
        for (int kk = 0; kk < 8; ++kk) {
            aq[kk] = cvt8s(*(const f32x4*)(qp + kk * 16),
                           *(const f32x4*)(qp + kk * 16 + 4), SCALE);
        }
    }

    // ---------------- pass 1: row sums (BK=128, 16 tiles) ----------------
    // Swapped MFMA: c = S^T (col = q = n31, rows = keys in regs) -> scalar
    // per-lane psum. Wave w owns keys w*32..w*32+31 of each tile.
    float psum = 0.f;
    {
        f32x4 kreg[16];
#pragma unroll
        for (int i = 0; i < 8; ++i) {
            int f = tid + i * 256, row = f >> 4, g = f & 15;
            const float* kp = Kb + (size_t)row * DH + g * 8;
            kreg[2 * i]     = *(const f32x4*)kp;
            kreg[2 * i + 1] = *(const f32x4*)(kp + 4);
        }
        for (int kt = 0; kt < 16; ++kt) {
            barrier_lgkm();   // prior-iter frag reads done
#pragma unroll
            for (int i = 0; i < 8; ++i) {
                int f = tid + i * 256, row = f >> 4, g = f & 15;
                *(bf16x8*)&Ks1[row][g * 8] = cvt8(kreg[2 * i], kreg[2 * i + 1]);
            }
            barrier_lgkm();   // staging visible
            if (kt + 1 < 16) {
#pragma unroll
                for (int i = 0; i < 8; ++i) {
                    int f = tid + i * 256, row = f >> 4, g = f & 15;
                    const float* kp = Kb + (size_t)((kt + 1) * 128 + row) * DH + g * 8;
                    kreg[2 * i]     = *(const f32x4*)kp;
                    kreg[2 * i + 1] = *(const f32x4*)(kp + 4);
                }
            }
            f32x16 c = (f32x16)0.0f;
#pragma unroll
            for (int kk = 0; kk < 8; ++kk) {
                bf16x8 kf = *(const bf16x8*)&Ks1[wave * 32 + n31][kk * 16 + h * 8];
                c = mfma32(kf, aq[kk], c);
            }
#pragma unroll
            for (int r = 0; r < 16; ++r) psum += __expf(c[r]);
        }
    }

    // prefetch pass-2 tile 0 (K/V re-reads are L2-hot); overlaps reduction
    const int dv = 2 * lane;          // V-stage: this lane owns d = dv, dv+1
    f32x4 kreg2[8];
    f32x2 vr0[8], vr1[8];             // [j] = V[k0+j][dv..dv+1]
#pragma unroll
    for (int i = 0; i < 4; ++i) {
        int f = tid + i * 256, row = f >> 4, g = f & 15;
        const float* kp = Kb + (size_t)row * DH + g * 8;
        kreg2[2 * i]     = *(const f32x4*)kp;
        kreg2[2 * i + 1] = *(const f32x4*)(kp + 4);
    }
#pragma unroll
    for (int j = 0; j < 8; ++j) {
        vr0[j] = *(const f32x2*)(Vb + (size_t)(8 * wave + j) * DH + dv);
        vr1[j] = *(const f32x2*)(Vb + (size_t)(8 * wave + 32 + j) * DH + dv);
    }

    // merge h key-halves (shfl), then the 4 wave key-groups via LDS
    psum += __shfl_xor(psum, 32);
    if (lane < 32) rsum[wave * 32 + n31] = psum;
    barrier_lgkm();
    const float rinv = 1.0f / (rsum[n31] + rsum[32 + n31] +
                               rsum[64 + n31] + rsum[96 + n31]);
    barrier_lgkm();   // rinv read complete before Ps (alias) is written

    f32x16 racc = (f32x16)0.0f;

    // ---------------- pass 2: P store + PV (BK=64, 32 tiles) ----------------
    for (int kt = 0; kt < 32; ++kt) {
        barrier_lgkm();   // A: prev-iter PV/P-store LDS reads done
        // stage K tile [k][d] (coalesced regs -> LDS)
#pragma unroll
        for (int i = 0; i < 4; ++i) {
            int f = tid + i * 256, row = f >> 4, g = f & 15;
            *(bf16x8*)&Ks[row][g * 8] = cvt8(kreg2[2 * i], kreg2[2 * i + 1]);
        }
        // stage V^T [d][k]: k-contiguous b128 writes into XOR-swizzled blocks
        {
            int sw = (dv >> 3) & 7;
            bf16x8 w0, w1;
#pragma unroll
            for (int j = 0; j < 8; ++j) { w0[j] = (bf16)vr0[j][0]; w1[j] = (bf16)vr0[j][1]; }
            int pb = wave ^ sw;
            *(bf16x8*)&Vt[dv][pb * 8]     = w0;
            *(bf16x8*)&Vt[dv + 1][pb * 8] = w1;
#pragma unroll
            for (int j = 0; j < 8; ++j) { w0[j] = (bf16)vr1[j][0]; w1[j] = (bf16)vr1[j][1]; }
            pb = (wave + 4) ^ sw;
            *(bf16x8*)&Vt[dv][pb * 8]     = w0;
            *(bf16x8*)&Vt[dv + 1][pb * 8] = w1;
        }
        barrier_lgkm();   // B: Ks/Vt visible

        // QK^T + softmax on waves 0,1 only (wn = key-half); waves 2,3 have
        // nothing to contribute here -- occupancy (4 blocks/CU) fills the gap.
        if (wave < 2) {
            f32x16 c = (f32x16)0.0f;
#pragma unroll
            for (int kk = 0; kk < 8; ++kk) {
                bf16x8 kf = *(const bf16x8*)&Ks[wn * 32 + n31][kk * 16 + h * 8];
                c = mfma32(kf, aq[kk], c);
            }
            // softmax -> Ps, 4x b64 writes (reg r -> key wn*32+(r&3)+8*(r>>2)+4h)
#pragma unroll
            for (int g = 0; g < 4; ++g) {
                bf16x4 pw;
                pw[0] = (bf16)(__expf(c[4 * g + 0]) * rinv);
                pw[1] = (bf16)(__expf(c[4 * g + 1]) * rinv);
                pw[2] = (bf16)(__expf(c[4 * g + 2]) * rinv);
                pw[3] = (bf16)(__expf(c[4 * g + 3]) * rinv);
                *(bf16x4*)&Ps[n31][wn * 32 + 4 * h + 8 * g] = pw;
            }
        }

        // prefetch next tile (issued before this iter's P stores)
        if (kt + 1 < 32) {
#pragma unroll
            for (int i = 0; i < 4; ++i) {
                int f = tid + i * 256, row = f >> 4, g = f & 15;
                const float* kp = Kb + (size_t)((kt + 1) * 64 + row) * DH + g * 8;
                kreg2[2 * i]     = *(const f32x4*)kp;
                kreg2[2 * i + 1] = *(const f32x4*)(kp + 4);
            }
            const float* vb = Vb + (size_t)(kt + 1) * 64 * DH + dv;
#pragma unroll
            for (int j = 0; j < 8; ++j) {
                vr0[j] = *(const f32x2*)(vb + (size_t)(8 * wave + j) * DH);
                vr1[j] = *(const f32x2*)(vb + (size_t)(8 * wave + 32 + j) * DH);
            }
        }
        barrier_lgkm();   // C: Ps visible (cross-wave for P store + PV A-frags)

        // P global store: 32 rows x 8 threads; lanes 0-7 cover 128B
        // contiguous per instruction (full-line NT stores)
        {
            int prow = tid >> 3, pc = tid & 7;
            float* dst = Pb + (size_t)prow * SLK + kt * 64;
#pragma unroll
            for (int u = 0; u < 2; ++u) {
                bf16x4 pv = *(const bf16x4*)&Ps[prow][u * 32 + pc * 4];
                f32x4 o;
                o[0] = (float)pv[0]; o[1] = (float)pv[1];
                o[2] = (float)pv[2]; o[3] = (float)pv[3];
                __builtin_nontemporal_store(o, (f32x4*)(dst + u * 32 + pc * 4));
            }
        }

        // PV: all 4 waves; R rows = 32 q, d-cols = wave*32 + n31
#pragma unroll
        for (int kk = 0; kk < 4; ++kk) {
            bf16x8 ap = *(const bf16x8*)&Ps[n31][kk * 16 + 8 * h];
            int d = wave * 32 + n31;
            int pb = (2 * kk + h) ^ ((d >> 3) & 7);
            bf16x8 bv = *(const bf16x8*)&Vt[d][pb * 8];
            racc = mfma32(ap, bv, racc);
        }
    }

    // epilogue: R store (C layout: col = wave*32+n31 = d, row per reg map)
#pragma unroll
    for (int r = 0; r < 16; ++r) {
        int row = (r & 3) + 8 * (r >> 2) + 4 * h;
        int d   = wave * 32 + n31;
        __builtin_nontemporal_store(racc[r], &Rb[(size_t)row * DH + d]);
    }
}

extern "C" void kernel_launch(void* const* d_in, const int* in_sizes, int n_in,
                              void* d_out, int out_size, void* d_ws, size_t ws_size,
                              hipStream_t stream) {
    (void)in_sizes; (void)n_in; (void)out_size; (void)d_ws; (void)ws_size;
    const float* Q = (const float*)d_in[0];
    const float* K = (const float*)d_in[1];
    const float* V = (const float*)d_in[2];
    float* R = (float*)d_out;
    float* P = (float*)d_out + (size_t)NB * SLQ * DH;

    dim3 grid(NB, SLQ / BQ);  // 1024 blocks, batch-major for XCD L2 locality
    attn_fused<<<grid, 256, 0, stream>>>(Q, K, V, R, P);
}

// Round 6
// 388.024 us; speedup vs baseline: 2.1616x; 1.3531x over previous
//
#include <hip/hip_runtime.h>

// Fused attention fwd: R = softmax(Q K^T / sqrt(D)) V, plus attn weights P.
// B=16, LQ=LK=2048, D=128, fp32 in/out.
//
// Round 9. r8 post-mortem: occupancy DID double (40.9%) but spills (VGPR
// squeezed to 64; +37MB deterministic scratch writes; FETCH +60MB) poisoned
// the test. This round: real 4 blocks/CU with ZERO spills by removing all
// staging registers/VALU:
//  - pre-pass kernel packs K and V^T into bf16 "LDS image" tiles in d_ws
//    (16MB), XOR-swizzled (inrow ^= (row&7)<<4) so linear global_load_lds
//    yields conflict-reduced LDS (rule: linear dest + inv-swz source + swz
//    read).
//  - main kernel stages via __builtin_amdgcn_global_load_lds (16B, zero
//    VGPR round-trip, no cvt): 8 gll/wave/iter. Reg demand ~90 -> no spill
//    at the launch_bounds(256,4) cap of 128.
//  - P-store issued AFTER the glls each iter -> hides gll latency; counted
//    s_waitcnt vmcnt(2) (never 0 mid-loop) leaves the 2 NT stores in
//    flight across the barrier.
// Kept: swapped QK^T (per-lane scalar softmax), lgkm-only barriers, BQ=32
// grid 1024 batch-major, full-line NT P stores, Ps in LDS for cross-wave PV.

#define NB  16
#define SLQ 2048
#define SLK 2048
#define DH  128
#define BQ  32
#define BK  64

typedef __bf16 bf16;
typedef bf16  bf16x8 __attribute__((ext_vector_type(8)));
typedef bf16  bf16x4 __attribute__((ext_vector_type(4)));
typedef float f32x4  __attribute__((ext_vector_type(4)));
typedef float f32x16 __attribute__((ext_vector_type(16)));

#define SCALE 0.088388347648318447f  // 1/sqrt(128)

__device__ __forceinline__ f32x16 mfma32(bf16x8 a, bf16x8 b, f32x16 c) {
    return __builtin_amdgcn_mfma_f32_32x32x16_bf16(a, b, c, 0, 0, 0);
}

__device__ __forceinline__ bf16x8 cvt8(f32x4 v0, f32x4 v1) {
    bf16x8 r;
    r[0] = (bf16)v0[0]; r[1] = (bf16)v0[1]; r[2] = (bf16)v0[2]; r[3] = (bf16)v0[3];
    r[4] = (bf16)v1[0]; r[5] = (bf16)v1[1]; r[6] = (bf16)v1[2]; r[7] = (bf16)v1[3];
    return r;
}

__device__ __forceinline__ bf16x8 cvt8s(f32x4 v0, f32x4 v1, float s) {
    bf16x8 r;
    r[0] = (bf16)(v0[0] * s); r[1] = (bf16)(v0[1] * s);
    r[2] = (bf16)(v0[2] * s); r[3] = (bf16)(v0[3] * s);
    r[4] = (bf16)(v1[0] * s); r[5] = (bf16)(v1[1] * s);
    r[6] = (bf16)(v1[2] * s); r[7] = (bf16)(v1[3] * s);
    return r;
}

// Workgroup barrier waiting only on LDS ops (lgkmcnt), NOT vmcnt.
__device__ __forceinline__ void barrier_lgkm() {
    asm volatile("s_waitcnt lgkmcnt(0)" ::: "memory");
    __builtin_amdgcn_s_barrier();
    asm volatile("" ::: "memory");
}

// async global->LDS, 16B per lane. LDS dest = wave-uniform base + lane*16.
__device__ __forceinline__ void gll16(const void* g, void* l) {
    __builtin_amdgcn_global_load_lds(
        (const __attribute__((address_space(1))) void*)g,
        (__attribute__((address_space(3))) void*)l, 16, 0, 0);
}

// ---------------- pre-pass: pack K, V^T as swizzled bf16 LDS images --------
// K image tile (per (b,kt), 16KB): content[row*256 + ((col*2)^((row&7)<<4))]
//   = bf16(K[b][kt*64+row][col]), row=key 0..63, col=d 0..127.
// V image tile (16KB): content[d*128 + ((k*2)^((d&7)<<4))]
//   = bf16(V[b][kt*64+k][d]), d 0..127, k 0..63.
__global__ __launch_bounds__(256)
void prepack(const float* __restrict__ K, const float* __restrict__ V,
             bf16* __restrict__ Kimg, bf16* __restrict__ Vimg) {
    const int b = blockIdx.x, kt = blockIdx.y;
    const int tid = threadIdx.x;
    const float* Kb = K + ((size_t)b * SLK + (size_t)kt * 64) * DH;
    const float* Vb = V + ((size_t)b * SLK + (size_t)kt * 64) * DH;
    char* kout = (char*)(Kimg) + ((size_t)b * 32 + kt) * 16384;
    char* vout = (char*)(Vimg) + ((size_t)b * 32 + kt) * 16384;

    // K: coalesced img writes; source col recovered via XOR involution
#pragma unroll
    for (int i = 0; i < 4; ++i) {
        int ib  = (tid + i * 256) * 16;           // img byte
        int row = ib >> 8;
        int src = (ib & 255) ^ ((row & 7) << 4);
        int col = src >> 1;                        // multiple of 8
        const float* kp = Kb + (size_t)row * DH + col;
        bf16x8 w = cvt8(*(const f32x4*)kp, *(const f32x4*)(kp + 4));
        *(bf16x8*)(kout + ib) = w;
    }

    // V: coalesced f32 stage into LDS, then transposed swizzled img writes
    __shared__ float Vf[64][132];                  // 528B rows (16B aligned)
#pragma unroll
    for (int i = 0; i < 8; ++i) {
        int u = tid + i * 256;                     // f32x4 unit 0..2047
        int k = u >> 5, c4 = (u & 31) * 4;
        *(f32x4*)&Vf[k][c4] = *(const f32x4*)(Vb + (size_t)k * DH + c4);
    }
    __syncthreads();
#pragma unroll
    for (int i = 0; i < 4; ++i) {
        int ib = (tid + i * 256) * 16;
        int d  = ib >> 7;
        int src = (ib & 127) ^ ((d & 7) << 4);
        int k0 = src >> 1;                         // multiple of 8
        bf16x8 w;
#pragma unroll
        for (int j = 0; j < 8; ++j) w[j] = (bf16)Vf[k0 + j][d];
        *(bf16x8*)(vout + ib) = w;
    }
}

// ---------------- main kernel ----------------------------------------------
__global__ __launch_bounds__(256, 4)
void attn_fused(const float* __restrict__ Q, const bf16* __restrict__ Kimg,
                const bf16* __restrict__ Vimg, float* __restrict__ Rout,
                float* __restrict__ Pout) {
    const int b = blockIdx.x, qt = blockIdx.y;   // batch-major: XCD = b % 8
    const int tid  = threadIdx.x;
    const int wave = tid >> 6, lane = tid & 63;
    const int n31 = lane & 31, h = lane >> 5;
    const int wn = wave & 1;                     // pass-2 QK key-half

    // LDS: KsB 16KB (pass1: 32KB over KsB+VtB) | VtB 16KB | Ps[32][72] 4.6KB
    __shared__ __align__(16) char smem[37376];
    char* KsB = smem;
    char* VtB = smem + 16384;
    bf16 (*Ps)[72] = (bf16(*)[72])(smem + 32768);
    float* rsum = (float*)(smem + 32768);        // alias over Ps (pass-1 tail)

    const float* Qb = Q + ((size_t)b * SLQ + (size_t)qt * BQ) * DH;
    const char* Kt0 = (const char*)Kimg + (size_t)b * SLK * DH * 2;  // 32 tiles
    const char* Vt0 = (const char*)Vimg + (size_t)b * SLK * DH * 2;
    float* Rb = Rout + ((size_t)b * SLQ + (size_t)qt * BQ) * DH;
    float* Pb = Pout + ((size_t)b * SLQ + (size_t)qt * BQ) * SLK;

    // Q B-frags (32 q rows, scale folded): per lane Q[n31][kk*16+8h..+7]
    bf16x8 aq[8];
    {
        const float* qp = Qb + (size_t)n31 * DH + h * 8;
#pragma unroll
        for (int kk = 0; kk < 8; ++kk)
            aq[kk] = cvt8s(*(const f32x4*)(qp + kk * 16),
                           *(const f32x4*)(qp + kk * 16 + 4), SCALE);
    }

    // ---------------- pass 1: row sums (BK=128, 16 tiles, gll-staged) ------
    {
        const char* src = Kt0 + wave * 8192 + lane * 16;
        char* dst = KsB + wave * 8192;
#pragma unroll
        for (int j = 0; j < 8; ++j) gll16(src + j * 1024, dst + j * 1024);
    }
    float psum = 0.f;
    const int key1 = wave * 32 + n31;            // 0..127 (img rows are linear)
    const char* kr1 = KsB + key1 * 256;
    const int sw1 = (key1 & 7) << 4;
    for (int kt = 0; kt < 16; ++kt) {
        asm volatile("s_waitcnt vmcnt(0)" ::: "memory");
        __builtin_amdgcn_s_barrier();            // staged tile visible
        asm volatile("" ::: "memory");
        f32x16 c = (f32x16)0.0f;
#pragma unroll
        for (int kk = 0; kk < 8; ++kk) {
            bf16x8 kf = *(const bf16x8*)(kr1 + ((kk * 32 + 16 * h) ^ sw1));
            c = mfma32(kf, aq[kk], c);
        }
        barrier_lgkm();                          // all frag reads done
        if (kt + 1 < 16) {
            const char* src = Kt0 + (size_t)(kt + 1) * 32768 + wave * 8192 + lane * 16;
            char* dst = KsB + wave * 8192;
#pragma unroll
            for (int j = 0; j < 8; ++j) gll16(src + j * 1024, dst + j * 1024);
        }
        asm volatile("" ::: "memory");
#pragma unroll
        for (int r = 0; r < 16; ++r) psum += __expf(c[r]);   // hides gll issue
    }

    // merge: h halves (shfl) then 4 wave key-groups via LDS; stage tile 0
    psum += __shfl_xor(psum, 32);
    {
        const char* ks = Kt0 + wave * 4096 + lane * 16;
        const char* vs = Vt0 + wave * 4096 + lane * 16;
        char* kd = KsB + wave * 4096;
        char* vd = VtB + wave * 4096;
#pragma unroll
        for (int j = 0; j < 4; ++j) {
            gll16(ks + j * 1024, kd + j * 1024);
            gll16(vs + j * 1024, vd + j * 1024);
        }
    }
    if (lane < 32) rsum[wave * 32 + n31] = psum;
    barrier_lgkm();                              // rsum visible
    const float rinv = 1.0f / (rsum[n31] + rsum[32 + n31] +
                               rsum[64 + n31] + rsum[96 + n31]);
    asm volatile("s_waitcnt vmcnt(0)" ::: "memory");
    barrier_lgkm();                              // tile0 visible; rsum reads done

    f32x16 racc = (f32x16)0.0f;
    const int key2 = wn * 32 + n31;
    const char* kr2 = KsB + key2 * 256;
    const int sw2 = (key2 & 7) << 4;
    const int dpv = wave * 32 + n31;
    const char* vr2 = VtB + dpv * 128;
    const int swv = (dpv & 7) << 4;

    // ---------------- pass 2: P store + PV (BK=64, 32 tiles) ---------------
    for (int kt = 0; kt < 32; ++kt) {
        // QK^T + softmax on waves 0,1 (key-half wn); c col = q (lane)
        if (wave < 2) {
            f32x16 c = (f32x16)0.0f;
#pragma unroll
            for (int kk = 0; kk < 8; ++kk) {
                bf16x8 kf = *(const bf16x8*)(kr2 + ((kk * 32 + 16 * h) ^ sw2));
                c = mfma32(kf, aq[kk], c);
            }
#pragma unroll
            for (int g = 0; g < 4; ++g) {
                bf16x4 pw;
                pw[0] = (bf16)(__expf(c[4 * g + 0]) * rinv);
                pw[1] = (bf16)(__expf(c[4 * g + 1]) * rinv);
                pw[2] = (bf16)(__expf(c[4 * g + 2]) * rinv);
                pw[3] = (bf16)(__expf(c[4 * g + 3]) * rinv);
                *(bf16x4*)&Ps[n31][wn * 32 + 4 * h + 8 * g] = pw;
            }
        }
        barrier_lgkm();   // C: Ps visible to all waves

        // PV: all 4 waves, d = wave*32+n31
#pragma unroll
        for (int kk = 0; kk < 4; ++kk) {
            bf16x8 ap = *(const bf16x8*)&Ps[n31][kk * 16 + 8 * h];
            bf16x8 bv = *(const bf16x8*)(vr2 + (((2 * kk + h) * 16) ^ swv));
            racc = mfma32(ap, bv, racc);
        }
        barrier_lgkm();   // A: all tile-kt Ks/Vt reads done -> restageable

        // stage tile kt+1 (8 glls, zero VGPR)
        if (kt + 1 < 32) {
            const char* ks = Kt0 + (size_t)(kt + 1) * 16384 + wave * 4096 + lane * 16;
            const char* vs = Vt0 + (size_t)(kt + 1) * 16384 + wave * 4096 + lane * 16;
            char* kd = KsB + wave * 4096;
            char* vd = VtB + wave * 4096;
#pragma unroll
            for (int j = 0; j < 4; ++j) {
                gll16(ks + j * 1024, kd + j * 1024);
                gll16(vs + j * 1024, vd + j * 1024);
            }
        }
        asm volatile("" ::: "memory");

        // P store of tile kt (hides gll latency). Lanes 0-7 cover 128B
        // contiguous per instruction -> full-line NT stores.
        {
            int prow = tid >> 3, pc = tid & 7;
            float* dst = Pb + (size_t)prow * SLK + kt * 64;
#pragma unroll
            for (int u = 0; u < 2; ++u) {
                bf16x4 pv = *(const bf16x4*)&Ps[prow][u * 32 + pc * 4];
                f32x4 o;
                o[0] = (float)pv[0]; o[1] = (float)pv[1];
                o[2] = (float)pv[2]; o[3] = (float)pv[3];
                __builtin_nontemporal_store(o, (f32x4*)(dst + u * 32 + pc * 4));
            }
        }
        asm volatile("" ::: "memory");

        // counted wait: queue = [<=2 old stores, 8 glls, 2 new stores];
        // vmcnt(2) -> glls complete, this iter's 2 NT stores stay in flight.
        if (kt + 1 < 32) asm volatile("s_waitcnt vmcnt(2)" ::: "memory");
        __builtin_amdgcn_s_barrier();   // B: staged tile kt+1 visible
        asm volatile("" ::: "memory");
    }

    // epilogue: R store (col = wave*32+n31 = d; row per C-frag reg map)
#pragma unroll
    for (int r = 0; r < 16; ++r) {
        int row = (r & 3) + 8 * (r >> 2) + 4 * h;
        __builtin_nontemporal_store(racc[r], &Rb[(size_t)row * DH + dpv]);
    }
}

extern "C" void kernel_launch(void* const* d_in, const int* in_sizes, int n_in,
                              void* d_out, int out_size, void* d_ws, size_t ws_size,
                              hipStream_t stream) {
    (void)in_sizes; (void)n_in; (void)out_size; (void)ws_size;
    const float* Q = (const float*)d_in[0];
    const float* K = (const float*)d_in[1];
    const float* V = (const float*)d_in[2];
    float* R = (float*)d_out;
    float* P = (float*)d_out + (size_t)NB * SLQ * DH;

    bf16* Kimg = (bf16*)d_ws;                                 // 8 MB
    bf16* Vimg = (bf16*)d_ws + (size_t)NB * SLK * DH;         // 8 MB

    prepack<<<dim3(NB, SLK / 64), 256, 0, stream>>>(K, V, Kimg, Vimg);
    attn_fused<<<dim3(NB, SLQ / BQ), 256, 0, stream>>>(Q, Kimg, Vimg, R, P);
}